// Round 18
// baseline (898.870 us; speedup 1.0000x reference)
//
#include <hip/hip_runtime.h>
#include <hip/hip_bf16.h>

// ---------------------------------------------------------------------------
// ScaledDotProductAttentionMemory, round 18:
//  - 2-PASS RECOMPUTE attention: pass 1 = QK^T+exp+rowsum (no P storage),
//    pass 2 = recompute exp, normalize by invq, att stores + PV with
//    pre-normalized bf16 P. Eliminates the 35 KB Pl stash -> LDS 17.8 KB ->
//    8 blocks/CU = 32 waves (~100% occupancy) = 2x loads in flight.
//    (Measured: 2.2 TB/s == 128 loads in flight; Little's law says the
//    only remaining deepening lever is blocks/CU.)
//  - mask loads back to CACHED (r17 NT-mask raised FETCH 347->400).
//  - K re-read in pass 2 is L2-resident (one bh per XCD group, 0.6 MB).
// Outputs: out (8,1024,1024) fp32 ; att (8,16,1024,1064) fp32
// ---------------------------------------------------------------------------

#define B_ 8
#define NQ 1024
#define NK 1024
#define DM 1024
#define H_ 16
#define DK 64
#define NKM 1064   // nk + M
#define NKP 1104   // padded row length for Kh/Vt

typedef __attribute__((ext_vector_type(8))) short bf16x8;
typedef __attribute__((ext_vector_type(4))) float f32x4;
typedef __attribute__((ext_vector_type(4))) short short4v;
typedef __attribute__((ext_vector_type(2))) unsigned int u32x2;

static __device__ __forceinline__ short f2bf(float x) {
    __hip_bfloat16 h = __float2bfloat16(x);
    return __builtin_bit_cast(short, h);
}
static __device__ __forceinline__ float bf2f(short s) {
    unsigned int u = ((unsigned int)(unsigned short)s) << 16;
    return __builtin_bit_cast(float, u);
}

static __device__ __forceinline__ bf16x8 pack8(const float* __restrict__ p) {
    float4 f0 = *(const float4*)p;
    float4 f1 = *(const float4*)(p + 4);
    bf16x8 a;
    a[0] = f2bf(f0.x); a[1] = f2bf(f0.y); a[2] = f2bf(f0.z); a[3] = f2bf(f0.w);
    a[4] = f2bf(f1.x); a[5] = f2bf(f1.y); a[6] = f2bf(f1.z); a[7] = f2bf(f1.w);
    return a;
}

// async global->LDS, 16B per lane; LDS dest is wave-uniform base + lane*16
static __device__ __forceinline__ void gload16(const short* g, short* l) {
    __builtin_amdgcn_global_load_lds(
        (__attribute__((address_space(1))) void*)const_cast<short*>(g),
        (__attribute__((address_space(3))) void*)l, 16, 0, 0);
}

// --- mask dtype probe: bool(1B) vs int32(4B) -------------------------------
__global__ void detect_mask_kernel(const unsigned int* __restrict__ m, int n_dwords,
                                   int* __restrict__ flag) {
    __shared__ int any_big;
    if (threadIdx.x == 0) any_big = 0;
    __syncthreads();
    for (int i = threadIdx.x; i < n_dwords; i += blockDim.x)
        if (m[i] > 1u) any_big = 1;
    __syncthreads();
    if (threadIdx.x == 0) *flag = any_big ? 0 : 1;   // 1 => int32, 0 => bytes
}

// --- W (K x N) fp32 -> WT (N x K) bf16 --------------------------------------
__global__ void transpose_w_kernel(const float* __restrict__ W, short* __restrict__ WT) {
    __shared__ float t[32][33];
    int tx = threadIdx.x & 31, ty = threadIdx.x >> 5;
    int k0 = blockIdx.x * 32, n0 = blockIdx.y * 32;
#pragma unroll
    for (int r = 0; r < 4; r++)
        t[ty + 8 * r][tx] = W[(size_t)(k0 + ty + 8 * r) * DM + n0 + tx];
    __syncthreads();
#pragma unroll
    for (int r = 0; r < 4; r++)
        WT[(size_t)(n0 + ty + 8 * r) * DM + k0 + tx] = f2bf(t[tx][ty + 8 * r]);
}

// --- fp32 -> bf16 convert of the 3 input tensors (contiguous dest) ----------
__global__ void convert_bf16_kernel(const float* __restrict__ a, const float* __restrict__ b,
                                    const float* __restrict__ c, short* __restrict__ out) {
    const size_t NT = (size_t)B_ * NQ * DM;          // 8388608 per tensor
    const size_t total = NT * 3;
    size_t i = ((size_t)blockIdx.x * 256 + threadIdx.x) * 8;
    const size_t step = (size_t)gridDim.x * 256 * 8;
    for (; i < total; i += step) {
        const float* src = (i < NT) ? (a + i) : (i < 2 * NT) ? (b + (i - NT)) : (c + (i - 2 * NT));
        *(bf16x8*)(out + i) = pack8(src);
    }
}

// --- memory-slot rows of Kh / Vt (rows 1024..1103; zeros past 1063) --------
__global__ void fill_mem_kernel(const float* __restrict__ m_k, const float* __restrict__ m_v,
                                short* __restrict__ Kh, short* __restrict__ Vt) {
    int blk = blockIdx.x;           // 128 bh * 20 row-groups
    int bh = blk / 20, rb = blk % 20;
    int r = rb * 4 + (threadIdx.x >> 6);    // 0..79
    int d = threadIdx.x & 63;
    int h = bh & 15;
    float kv = 0.f, vv = 0.f;
    if (r < 40) {
        kv = 8.0f * m_k[(size_t)(r * H_ + h) * DK + d];               // sqrt(DK)=8
        vv = 6.324555320336759f * m_v[(size_t)(r * H_ + h) * DK + d]; // sqrt(M)
    }
    int kk = 1024 + r;
    Kh[((size_t)bh * NKP + kk) * 64 + d] = f2bf(kv);
    Vt[((size_t)bh * 64 + d) * NKP + kk] = f2bf(vv);
}

// ---------------------------------------------------------------------------
// m97-style GEMM: C[8192x1024] = A(bf16) @ BT^T + bias.
// MODE 0 scales the output by 0.125 (1/sqrt(dk), power of two => bf16-exact).
// ---------------------------------------------------------------------------
template <int MODE>
__global__ __launch_bounds__(256) void gemm_tile_kernel(
    const short* __restrict__ Ab, const short* __restrict__ BT,
    const float* __restrict__ bias,
    float* __restrict__ outF, short* __restrict__ outB) {
    __shared__ short As[2][4096];   // [128][32] linear
    __shared__ short Bs[2][4096];

    const int tid = threadIdx.x;
    const int lane = tid & 63;
    const int wid = tid >> 6;
    int swz = (blockIdx.x & 7) * 64 + (blockIdx.x >> 3);
    const int mt = swz >> 3, nt = swz & 7;
    const int brow = mt * 128, bcol = nt * 128;
    const int wr = wid >> 1, wc = wid & 1;
    const int l15 = lane & 15, lg = lane >> 4;

    f32x4 acc[4][4];
#pragma unroll
    for (int m = 0; m < 4; m++)
#pragma unroll
        for (int n = 0; n < 4; n++) acc[m][n] = f32x4{0.f, 0.f, 0.f, 0.f};

    auto stage = [&](int buf, int k0) {
#pragma unroll
        for (int i = 0; i < 2; i++) {
            int c = tid + i * 256;               // 16B chunk id, 0..511
            int row = c >> 2, slot = c & 3;
            int base = (c & ~63) * 8;            // wave-uniform LDS short offset
            gload16(Ab + (size_t)(brow + row) * DM + k0 + slot * 8, &As[buf][base]);
            gload16(BT + (size_t)(bcol + row) * DM + k0 + slot * 8, &Bs[buf][base]);
        }
    };

    stage(0, 0);
    for (int kt = 0; kt < 32; ++kt) {
        __syncthreads();                         // drains gload of buf[kt&1]
        if (kt + 1 < 32) stage((kt + 1) & 1, (kt + 1) * 32);
        const short* Ab_ = As[kt & 1];
        const short* Bb_ = Bs[kt & 1];
        bf16x8 a[4], b[4];
#pragma unroll
        for (int m = 0; m < 4; m++)
            a[m] = *(const bf16x8*)(Ab_ + (wr * 64 + m * 16 + l15) * 32 + lg * 8);
#pragma unroll
        for (int n = 0; n < 4; n++)
            b[n] = *(const bf16x8*)(Bb_ + (wc * 64 + n * 16 + l15) * 32 + lg * 8);
#pragma unroll
        for (int m = 0; m < 4; m++)
#pragma unroll
            for (int n = 0; n < 4; n++)
                acc[m][n] = __builtin_amdgcn_mfma_f32_16x16x32_bf16(a[m], b[n], acc[m][n], 0, 0, 0);
    }

#pragma unroll
    for (int n = 0; n < 4; n++) {
        int col = bcol + wc * 64 + n * 16 + l15;
        float bval = bias[col];
#pragma unroll
        for (int m = 0; m < 4; m++) {
            int row0 = brow + wr * 64 + m * 16 + lg * 4;
            if (MODE == 3) {
#pragma unroll
                for (int r = 0; r < 4; r++)
                    outF[(size_t)(row0 + r) * DM + col] = acc[m][n][r] + bval;
            } else if (MODE == 0) {
                int h = col >> 6, d = col & 63;
#pragma unroll
                for (int r = 0; r < 4; r++) {
                    int row = row0 + r;
                    int b = row >> 10, q = row & 1023;
                    outB[((size_t)(b * H_ + h) * NQ + q) * 64 + d] =
                        f2bf((acc[m][n][r] + bval) * 0.125f);   // fold 1/sqrt(dk)
                }
            } else if (MODE == 1) {
                int h = col >> 6, d = col & 63;
#pragma unroll
                for (int r = 0; r < 4; r++) {
                    int row = row0 + r;
                    int b = row >> 10, kk = row & 1023;
                    outB[((size_t)(b * H_ + h) * NKP + kk) * 64 + d] = f2bf(acc[m][n][r] + bval);
                }
            } else {  // MODE 2: Vt[bh][d][kk]
                int h = col >> 6, d = col & 63;
                int b = row0 >> 10, kk0 = row0 & 1023;
                short4v sv;
#pragma unroll
                for (int r = 0; r < 4; r++) sv[r] = f2bf(acc[m][n][r] + bval);
                *(short4v*)(outB + ((size_t)(b * H_ + h) * 64 + d) * NKP + kk0) = sv;
            }
        }
    }
}

// ---------------------------------------------------------------------------
// FUSED attention, 2-PASS RECOMPUTE (no P storage). Block = 4 waves x same
// 16 q; wave w owns kk window [w*272, w*272+272). Interleaved K-row trick:
// QK^T C-frag of lane (l15=q,lg) holds kk = base+8*lg+{0..7} = PV A-layout.
// Pass 1: rowsum only. Pass 2: recompute exp, att NT stores (normalized),
// PV with PRE-NORMALIZED bf16 P (O needs no final scale).
// LDS = 17.8 KB -> 8 blocks/CU (32 waves, ~100% occupancy).
// ---------------------------------------------------------------------------
__global__ __launch_bounds__(256) void attn_fused_kernel(
    const short* __restrict__ Qh, const short* __restrict__ Kh,
    const short* __restrict__ Vt,
    const unsigned char* __restrict__ mb, const int* __restrict__ mi,
    const int* __restrict__ flag,
    float* __restrict__ att, short* __restrict__ Ow) {
    __shared__ float Ored[4][16][68];   // 17408 B (O cross-wave reduce)
    __shared__ float redS[4][16];       // per-wave rowsums
    __shared__ float invS[16];          // 1/total rowsum per q

    // XCD swizzle: 64 consecutive blocks (one bh) per XCD
    int swz = (blockIdx.x & 7) * 1024 + (blockIdx.x >> 3);
    int bh = swz >> 6;
    int q0 = (swz & 63) * 16;
    int wid = threadIdx.x >> 6;
    int lane = threadIdx.x & 63;
    int l15 = lane & 15, lg = lane >> 4;

    const short* Qb = Qh + (size_t)bh * NQ * 64;
    const short* Kb = Kh + (size_t)bh * NKP * 64;
    const short* Vb = Vt + (size_t)bh * 64 * NKP;
    const int is32 = *flag;

    // Q fragments (B-operand of swapped QK^T): row = q0 + l15 (pre-scaled 1/8)
    bf16x8 aq0 = *(const bf16x8*)(Qb + (size_t)(q0 + l15) * 64 + lg * 8);
    bf16x8 aq1 = *(const bf16x8*)(Qb + (size_t)(q0 + l15) * 64 + 32 + lg * 8);

    size_t qrow = (size_t)bh * NQ + q0 + l15;
    const int kkw = wid * 272;                       // wave's kk window
    const int rofs = ((l15 >> 2) << 3) + (l15 & 3);  // interleaved K-row offset

    auto loadMask = [&](int kkb) -> u32x2 {
        if (kkb >= NK) return u32x2{0u, 0u};
        if (is32) {
            int4 ma = *(const int4*)(mi + qrow * NK + kkb);
            int4 mc = *(const int4*)(mi + qrow * NK + kkb + 4);
            unsigned mlo = (ma.x ? 1u : 0u) | (ma.y ? 0x100u : 0u) |
                           (ma.z ? 0x10000u : 0u) | (ma.w ? 0x1000000u : 0u);
            unsigned mhi = (mc.x ? 1u : 0u) | (mc.y ? 0x100u : 0u) |
                           (mc.z ? 0x10000u : 0u) | (mc.w ? 0x1000000u : 0u);
            return u32x2{mlo, mhi};
        }
        return *(const u32x2*)(mb + qrow * NK + kkb);
    };

    // ================= PASS 1: rowsum only ================================
    float rs = 0.f;
#pragma unroll
    for (int pp = 0; pp < 9; ++pp) {
        int ofs = pp * 32 + lg * 8;
        int base = kkw + pp * 32;
        int kkb = base + lg * 8;
        const short* Kr0 = Kb + (size_t)(base + rofs) * 64;
        bf16x8 k0a = *(const bf16x8*)(Kr0 + lg * 8);
        bf16x8 k0b = *(const bf16x8*)(Kr0 + 32 + lg * 8);
        bf16x8 k1a = *(const bf16x8*)(Kr0 + 256 + lg * 8);
        bf16x8 k1b = *(const bf16x8*)(Kr0 + 256 + 32 + lg * 8);
        u32x2 mu = loadMask(kkb);
        f32x4 s0 = {0.f, 0.f, 0.f, 0.f}, s1 = {0.f, 0.f, 0.f, 0.f};
        s0 = __builtin_amdgcn_mfma_f32_16x16x32_bf16(k0a, aq0, s0, 0, 0, 0);
        s0 = __builtin_amdgcn_mfma_f32_16x16x32_bf16(k0b, aq1, s0, 0, 0, 0);
        s1 = __builtin_amdgcn_mfma_f32_16x16x32_bf16(k1a, aq0, s1, 0, 0, 0);
        s1 = __builtin_amdgcn_mfma_f32_16x16x32_bf16(k1b, aq1, s1, 0, 0, 0);
        bool live = (kkb < NKM) && (ofs < 272);
#pragma unroll
        for (int r = 0; r < 4; r++)
            rs += (live && (((mu[0] >> (8 * r)) & 0xffu) == 0u)) ? __expf(s0[r]) : 0.f;
#pragma unroll
        for (int r = 0; r < 4; r++)
            rs += (live && (((mu[1] >> (8 * r)) & 0xffu) == 0u)) ? __expf(s1[r]) : 0.f;
    }
    rs += __shfl_xor(rs, 16);
    rs += __shfl_xor(rs, 32);
    if (lg == 0) redS[wid][l15] = rs;
    __syncthreads();
    if (threadIdx.x < 16)
        invS[threadIdx.x] = 1.f / (redS[0][threadIdx.x] + redS[1][threadIdx.x] +
                                   redS[2][threadIdx.x] + redS[3][threadIdx.x]);
    __syncthreads();
    float invq = invS[l15];                      // this lane's q = l15

    // ================= PASS 2: recompute + att + PV =======================
    f32x4 po[4];
#pragma unroll
    for (int dt = 0; dt < 4; dt++) po[dt] = f32x4{0.f, 0.f, 0.f, 0.f};

#pragma unroll
    for (int pp = 0; pp < 9; ++pp) {
        int ofs = pp * 32 + lg * 8;
        int base = kkw + pp * 32;
        int kkb = base + lg * 8;
        const short* Kr0 = Kb + (size_t)(base + rofs) * 64;
        bf16x8 k0a = *(const bf16x8*)(Kr0 + lg * 8);
        bf16x8 k0b = *(const bf16x8*)(Kr0 + 32 + lg * 8);
        bf16x8 k1a = *(const bf16x8*)(Kr0 + 256 + lg * 8);
        bf16x8 k1b = *(const bf16x8*)(Kr0 + 256 + 32 + lg * 8);
        bf16x8 bv0 = *(const bf16x8*)(Vb + (size_t)(l15) * NKP + kkb);
        bf16x8 bv1 = *(const bf16x8*)(Vb + (size_t)(16 + l15) * NKP + kkb);
        bf16x8 bv2 = *(const bf16x8*)(Vb + (size_t)(32 + l15) * NKP + kkb);
        bf16x8 bv3 = *(const bf16x8*)(Vb + (size_t)(48 + l15) * NKP + kkb);
        u32x2 mu = loadMask(kkb);
        f32x4 s0 = {0.f, 0.f, 0.f, 0.f}, s1 = {0.f, 0.f, 0.f, 0.f};
        __builtin_amdgcn_s_setprio(1);
        s0 = __builtin_amdgcn_mfma_f32_16x16x32_bf16(k0a, aq0, s0, 0, 0, 0);
        s0 = __builtin_amdgcn_mfma_f32_16x16x32_bf16(k0b, aq1, s0, 0, 0, 0);
        s1 = __builtin_amdgcn_mfma_f32_16x16x32_bf16(k1a, aq0, s1, 0, 0, 0);
        s1 = __builtin_amdgcn_mfma_f32_16x16x32_bf16(k1b, aq1, s1, 0, 0, 0);
        bool live = (kkb < NKM) && (ofs < 272);
        bf16x8 pa;
        f32x4 w0, w1;
#pragma unroll
        for (int r = 0; r < 4; r++) {
            float e = (live && (((mu[0] >> (8 * r)) & 0xffu) == 0u)) ? __expf(s0[r]) : 0.f;
            float en = e * invq;
            w0[r] = en;
            pa[r] = f2bf(en);
        }
#pragma unroll
        for (int r = 0; r < 4; r++) {
            float e = (live && (((mu[1] >> (8 * r)) & 0xffu) == 0u)) ? __expf(s1[r]) : 0.f;
            float en = e * invq;
            w1[r] = en;
            pa[4 + r] = f2bf(en);
        }
        // att stores: 2x16B NT per lane (kkb multiple of 8 -> 32B aligned)
        if (live) {
            float* ap = att + qrow * NKM + kkb;
            __builtin_nontemporal_store(w0, (f32x4*)ap);
            __builtin_nontemporal_store(w1, (f32x4*)(ap + 4));
        }
        // PV with pre-normalized P (O needs no final scale)
        po[0] = __builtin_amdgcn_mfma_f32_16x16x32_bf16(pa, bv0, po[0], 0, 0, 0);
        po[1] = __builtin_amdgcn_mfma_f32_16x16x32_bf16(pa, bv1, po[1], 0, 0, 0);
        po[2] = __builtin_amdgcn_mfma_f32_16x16x32_bf16(pa, bv2, po[2], 0, 0, 0);
        po[3] = __builtin_amdgcn_mfma_f32_16x16x32_bf16(pa, bv3, po[3], 0, 0, 0);
        __builtin_amdgcn_s_setprio(0);
    }

    // ---- cross-wave O reduce ----
#pragma unroll
    for (int dt = 0; dt < 4; dt++)
#pragma unroll
        for (int r = 0; r < 4; r++)
            Ored[wid][lg * 4 + r][dt * 16 + l15] = po[dt][r];
    __syncthreads();

    int tq = threadIdx.x >> 4;                  // 0..15
    int d0 = (threadIdx.x & 15) * 4;            // 0..60
    float4 o = {0.f, 0.f, 0.f, 0.f};
#pragma unroll
    for (int w = 0; w < 4; w++) {
        float4 v = *(const float4*)(&Ored[w][tq][d0]);
        o.x += v.x; o.y += v.y; o.z += v.z; o.w += v.w;
    }
    int b = bh >> 4, h = bh & 15;
    short4v sv;
    sv[0] = f2bf(o.x); sv[1] = f2bf(o.y);
    sv[2] = f2bf(o.z); sv[3] = f2bf(o.w);
    *(short4v*)(Ow + ((size_t)b * NQ + q0 + tq) * DM + h * 64 + d0) = sv;
}

extern "C" void kernel_launch(void* const* d_in, const int* in_sizes, int n_in,
                              void* d_out, int out_size, void* d_ws, size_t ws_size,
                              hipStream_t stream) {
    const float* queries = (const float*)d_in[0];
    const float* keys    = (const float*)d_in[1];
    const float* values  = (const float*)d_in[2];
    const void*  mask    = d_in[3];
    const float* Wq = (const float*)d_in[4];
    const float* bq = (const float*)d_in[5];
    const float* Wk = (const float*)d_in[6];
    const float* bk = (const float*)d_in[7];
    const float* Wv = (const float*)d_in[8];
    const float* bv = (const float*)d_in[9];
    const float* Wo = (const float*)d_in[10];
    const float* bo = (const float*)d_in[11];
    const float* m_k = (const float*)d_in[12];
    const float* m_v = (const float*)d_in[13];

    // workspace layout (~130 MB)
    short* WqT = (short*)d_ws;
    short* WkT = WqT + (size_t)DM * DM;
    short* WvT = WkT + (size_t)DM * DM;
    short* WoT = WvT + (size_t)DM * DM;
    short* Qh  = WoT + (size_t)DM * DM;                 // [128][1024][64]
    short* Kh  = Qh + (size_t)B_ * H_ * NQ * DK;        // [128][1104][64]
    short* Vt  = Kh + (size_t)B_ * H_ * NKP * DK;       // [128][64][1104]
    short* Ow  = Vt + (size_t)B_ * H_ * DK * NKP;       // [8192][1024]
    char*  after = (char*)(Ow + (size_t)B_ * NQ * DM);
    int*   flag = (int*)after;
    short* Qbf  = (short*)(after + 64);                 // bf16 q/k/v inputs
    short* Kbf  = Qbf + (size_t)B_ * NQ * DM;
    short* Vbf  = Kbf + (size_t)B_ * NQ * DM;

    float* outO = (float*)d_out;                         // 8*1024*1024
    float* att  = outO + (size_t)B_ * NQ * DM;           // 8*16*1024*1064

    detect_mask_kernel<<<1, 256, 0, stream>>>((const unsigned int*)mask, 4096, flag);

    dim3 tg(32, 32);
    transpose_w_kernel<<<tg, 256, 0, stream>>>(Wq, WqT);
    transpose_w_kernel<<<tg, 256, 0, stream>>>(Wk, WkT);
    transpose_w_kernel<<<tg, 256, 0, stream>>>(Wv, WvT);
    transpose_w_kernel<<<tg, 256, 0, stream>>>(Wo, WoT);

    convert_bf16_kernel<<<4096, 256, 0, stream>>>(queries, keys, values, Qbf);

    gemm_tile_kernel<0><<<512, 256, 0, stream>>>(Qbf, WqT, bq, nullptr, Qh);
    gemm_tile_kernel<1><<<512, 256, 0, stream>>>(Kbf, WkT, bk, nullptr, Kh);
    gemm_tile_kernel<2><<<512, 256, 0, stream>>>(Vbf, WvT, bv, nullptr, Vt);

    fill_mem_kernel<<<2560, 256, 0, stream>>>(m_k, m_v, Kh, Vt);

    attn_fused_kernel<<<8192, 256, 0, stream>>>(Qh, Kh, Vt,
                                                (const unsigned char*)mask, (const int*)mask,
                                                flag, att, Ow);

    gemm_tile_kernel<3><<<512, 256, 0, stream>>>(Ow, WoT, bo, outO, nullptr);
}

// Round 19
// 636.037 us; speedup vs baseline: 1.4132x; 1.4132x over previous
//
#include <hip/hip_runtime.h>
#include <hip/hip_bf16.h>

// ---------------------------------------------------------------------------
// ScaledDotProductAttentionMemory, round 19:
//  - attn: EXACT r14 body (best measured: 466 us; every deepening lever —
//    reg pipeline x3, 8-wave, 2-pass recompute — measured dead on this HW).
//  - gemm_tile<2> (V projection) epilogue: per-wave LDS transpose of the
//    64kk x 16d tile (reuses staging LDS, free after K-loop) -> 16 B/lane
//    stores covering full 128 B lines per Vt row. Kills the ~8x TCC write
//    amplification of the old scattered 8 B stores.
//  - 4 weight transposes batched into one launch (grid.z).
// Outputs: out (8,1024,1024) fp32 ; att (8,16,1024,1064) fp32
// ---------------------------------------------------------------------------

#define B_ 8
#define NQ 1024
#define NK 1024
#define DM 1024
#define H_ 16
#define DK 64
#define NKM 1064   // nk + M
#define NKP 1104   // padded row length for Kh/Vt
#define PSTR 280   // P LDS row stride in shorts (560 B)

typedef __attribute__((ext_vector_type(8))) short bf16x8;
typedef __attribute__((ext_vector_type(4))) float f32x4;
typedef __attribute__((ext_vector_type(4))) short short4v;
typedef __attribute__((ext_vector_type(2))) unsigned int u32x2;

static __device__ __forceinline__ short f2bf(float x) {
    __hip_bfloat16 h = __float2bfloat16(x);
    return __builtin_bit_cast(short, h);
}
static __device__ __forceinline__ float bf2f(short s) {
    unsigned int u = ((unsigned int)(unsigned short)s) << 16;
    return __builtin_bit_cast(float, u);
}

static __device__ __forceinline__ bf16x8 pack8(const float* __restrict__ p) {
    float4 f0 = *(const float4*)p;
    float4 f1 = *(const float4*)(p + 4);
    bf16x8 a;
    a[0] = f2bf(f0.x); a[1] = f2bf(f0.y); a[2] = f2bf(f0.z); a[3] = f2bf(f0.w);
    a[4] = f2bf(f1.x); a[5] = f2bf(f1.y); a[6] = f2bf(f1.z); a[7] = f2bf(f1.w);
    return a;
}

// async global->LDS, 16B per lane; LDS dest is wave-uniform base + lane*16
static __device__ __forceinline__ void gload16(const short* g, short* l) {
    __builtin_amdgcn_global_load_lds(
        (__attribute__((address_space(1))) void*)const_cast<short*>(g),
        (__attribute__((address_space(3))) void*)l, 16, 0, 0);
}

// --- mask dtype probe: bool(1B) vs int32(4B) -------------------------------
__global__ void detect_mask_kernel(const unsigned int* __restrict__ m, int n_dwords,
                                   int* __restrict__ flag) {
    __shared__ int any_big;
    if (threadIdx.x == 0) any_big = 0;
    __syncthreads();
    for (int i = threadIdx.x; i < n_dwords; i += blockDim.x)
        if (m[i] > 1u) any_big = 1;
    __syncthreads();
    if (threadIdx.x == 0) *flag = any_big ? 0 : 1;   // 1 => int32, 0 => bytes
}

// --- W (K x N) fp32 -> WT (N x K) bf16, 4 weights batched via blockIdx.z ---
__global__ void transpose_w_kernel(const float* __restrict__ W0, short* __restrict__ T0,
                                   const float* __restrict__ W1, short* __restrict__ T1,
                                   const float* __restrict__ W2, short* __restrict__ T2,
                                   const float* __restrict__ W3, short* __restrict__ T3) {
    const float* W = (blockIdx.z == 0) ? W0 : (blockIdx.z == 1) ? W1
                   : (blockIdx.z == 2) ? W2 : W3;
    short* WT = (blockIdx.z == 0) ? T0 : (blockIdx.z == 1) ? T1
              : (blockIdx.z == 2) ? T2 : T3;
    __shared__ float t[32][33];
    int tx = threadIdx.x & 31, ty = threadIdx.x >> 5;
    int k0 = blockIdx.x * 32, n0 = blockIdx.y * 32;
#pragma unroll
    for (int r = 0; r < 4; r++)
        t[ty + 8 * r][tx] = W[(size_t)(k0 + ty + 8 * r) * DM + n0 + tx];
    __syncthreads();
#pragma unroll
    for (int r = 0; r < 4; r++)
        WT[(size_t)(n0 + ty + 8 * r) * DM + k0 + tx] = f2bf(t[tx][ty + 8 * r]);
}

// --- fp32 -> bf16 convert of the 3 input tensors (contiguous dest) ----------
__global__ void convert_bf16_kernel(const float* __restrict__ a, const float* __restrict__ b,
                                    const float* __restrict__ c, short* __restrict__ out) {
    const size_t NT = (size_t)B_ * NQ * DM;          // 8388608 per tensor
    const size_t total = NT * 3;
    size_t i = ((size_t)blockIdx.x * 256 + threadIdx.x) * 8;
    const size_t step = (size_t)gridDim.x * 256 * 8;
    for (; i < total; i += step) {
        const float* src = (i < NT) ? (a + i) : (i < 2 * NT) ? (b + (i - NT)) : (c + (i - 2 * NT));
        *(bf16x8*)(out + i) = pack8(src);
    }
}

// --- memory-slot rows of Kh / Vt (rows 1024..1103; zeros past 1063) --------
__global__ void fill_mem_kernel(const float* __restrict__ m_k, const float* __restrict__ m_v,
                                short* __restrict__ Kh, short* __restrict__ Vt) {
    int blk = blockIdx.x;           // 128 bh * 20 row-groups
    int bh = blk / 20, rb = blk % 20;
    int r = rb * 4 + (threadIdx.x >> 6);    // 0..79
    int d = threadIdx.x & 63;
    int h = bh & 15;
    float kv = 0.f, vv = 0.f;
    if (r < 40) {
        kv = 8.0f * m_k[(size_t)(r * H_ + h) * DK + d];               // sqrt(DK)=8
        vv = 6.324555320336759f * m_v[(size_t)(r * H_ + h) * DK + d]; // sqrt(M)
    }
    int kk = 1024 + r;
    Kh[((size_t)bh * NKP + kk) * 64 + d] = f2bf(kv);
    Vt[((size_t)bh * 64 + d) * NKP + kk] = f2bf(vv);
}

// ---------------------------------------------------------------------------
// m97-style GEMM: C[8192x1024] = A(bf16) @ BT^T + bias.
// MODE 2 epilogue transposes each wave's 64kk x 16d tile in LDS (staging
// buffers are free after the K-loop) and stores 16 B/lane -> full 128 B
// line coverage per Vt row (old path: scattered 8 B partial-line stores).
// ---------------------------------------------------------------------------
template <int MODE>
__global__ __launch_bounds__(256) void gemm_tile_kernel(
    const short* __restrict__ Ab, const short* __restrict__ BT,
    const float* __restrict__ bias,
    float* __restrict__ outF, short* __restrict__ outB) {
    __shared__ short As[2][4096];   // [128][32] linear
    __shared__ short Bs[2][4096];

    const int tid = threadIdx.x;
    const int lane = tid & 63;
    const int wid = tid >> 6;
    int swz = (blockIdx.x & 7) * 64 + (blockIdx.x >> 3);
    const int mt = swz >> 3, nt = swz & 7;
    const int brow = mt * 128, bcol = nt * 128;
    const int wr = wid >> 1, wc = wid & 1;
    const int l15 = lane & 15, lg = lane >> 4;

    f32x4 acc[4][4];
#pragma unroll
    for (int m = 0; m < 4; m++)
#pragma unroll
        for (int n = 0; n < 4; n++) acc[m][n] = f32x4{0.f, 0.f, 0.f, 0.f};

    auto stage = [&](int buf, int k0) {
#pragma unroll
        for (int i = 0; i < 2; i++) {
            int c = tid + i * 256;               // 16B chunk id, 0..511
            int row = c >> 2, slot = c & 3;
            int base = (c & ~63) * 8;            // wave-uniform LDS short offset
            gload16(Ab + (size_t)(brow + row) * DM + k0 + slot * 8, &As[buf][base]);
            gload16(BT + (size_t)(bcol + row) * DM + k0 + slot * 8, &Bs[buf][base]);
        }
    };

    stage(0, 0);
    for (int kt = 0; kt < 32; ++kt) {
        __syncthreads();                         // drains gload of buf[kt&1]
        if (kt + 1 < 32) stage((kt + 1) & 1, (kt + 1) * 32);
        const short* Ab_ = As[kt & 1];
        const short* Bb_ = Bs[kt & 1];
        bf16x8 a[4], b[4];
#pragma unroll
        for (int m = 0; m < 4; m++)
            a[m] = *(const bf16x8*)(Ab_ + (wr * 64 + m * 16 + l15) * 32 + lg * 8);
#pragma unroll
        for (int n = 0; n < 4; n++)
            b[n] = *(const bf16x8*)(Bb_ + (wc * 64 + n * 16 + l15) * 32 + lg * 8);
#pragma unroll
        for (int m = 0; m < 4; m++)
#pragma unroll
            for (int n = 0; n < 4; n++)
                acc[m][n] = __builtin_amdgcn_mfma_f32_16x16x32_bf16(a[m], b[n], acc[m][n], 0, 0, 0);
    }
    // NOTE: last compute reads As[1]/Bs[1]; As[0]/Bs[0] are free for reuse.

#pragma unroll
    for (int n = 0; n < 4; n++) {
        int col = bcol + wc * 64 + n * 16 + l15;
        float bval = bias[col];
        if (MODE == 2) {
            // --- transpose 64kk x 16d wave tile in LDS, coalesced stores ---
            // wave-private region: waves 0,1 in As[0], waves 2,3 in Bs[0]
            short* T = (wid < 2) ? &As[0][wid * 1088] : &Bs[0][(wid - 2) * 1088];
#pragma unroll
            for (int m = 0; m < 4; m++) {
                short4v t4;
#pragma unroll
                for (int r = 0; r < 4; r++) t4[r] = f2bf(acc[m][n][r] + bval);
                // T[d=l15][kk = m*16+lg*4 .. +3], row stride 68 shorts
                *(short4v*)(&T[l15 * 68 + m * 16 + lg * 4]) = t4;
            }
            // read back: lane -> d = lane&15, chunk = lane>>4 (8 kk each)
            int dloc = lane & 15, c8 = lane >> 4;
            int rowbase = brow + wr * 64;            // 64 kk handled by this wave
            int bb = rowbase >> 10, kkw0 = rowbase & 1023;
            int colbase = bcol + wc * 64 + n * 16;   // 16 consecutive d, same h
            int hh = colbase >> 6, d0 = colbase & 63;
            short* vrow = outB + ((size_t)(bb * H_ + hh) * 64 + d0 + dloc) * NKP + kkw0;
            *(bf16x8*)(vrow + c8 * 8)      = *(const bf16x8*)(&T[dloc * 68 + c8 * 8]);
            *(bf16x8*)(vrow + 32 + c8 * 8) = *(const bf16x8*)(&T[dloc * 68 + 32 + c8 * 8]);
        } else {
#pragma unroll
            for (int m = 0; m < 4; m++) {
                int row0 = brow + wr * 64 + m * 16 + lg * 4;
                if (MODE == 3) {
#pragma unroll
                    for (int r = 0; r < 4; r++)
                        outF[(size_t)(row0 + r) * DM + col] = acc[m][n][r] + bval;
                } else if (MODE == 0) {
                    int h = col >> 6, d = col & 63;
#pragma unroll
                    for (int r = 0; r < 4; r++) {
                        int row = row0 + r;
                        int b = row >> 10, q = row & 1023;
                        outB[((size_t)(b * H_ + h) * NQ + q) * 64 + d] = f2bf(acc[m][n][r] + bval);
                    }
                } else {  // MODE 1
                    int h = col >> 6, d = col & 63;
#pragma unroll
                    for (int r = 0; r < 4; r++) {
                        int row = row0 + r;
                        int b = row >> 10, kk = row & 1023;
                        outB[((size_t)(b * H_ + h) * NKP + kk) * 64 + d] = f2bf(acc[m][n][r] + bval);
                    }
                }
            }
        }
    }
}

// ---------------------------------------------------------------------------
// FUSED attention (EXACT r14 body, best measured). Block = 4 waves x same
// 16 q; wave w owns kk window [w*272, w*272+272). Interleaved K-row trick:
// QK^T C-frag of lane (l15=q,lg) holds kk = base+8*lg+{0..7} = PV A-layout.
// P in wave-private LDS; att written post-barrier as aligned NT sweep.
// ---------------------------------------------------------------------------
__global__ __launch_bounds__(256, 4) void attn_fused_kernel(
    const short* __restrict__ Qh, const short* __restrict__ Kh,
    const short* __restrict__ Vt,
    const unsigned char* __restrict__ mb, const int* __restrict__ mi,
    const int* __restrict__ flag,
    float* __restrict__ att, short* __restrict__ Ow) {
    __shared__ short Pl[4][16][PSTR];   // wave-private unnormalized P (bf16)
    __shared__ float redS[4][16];       // per-wave rowsums
    __shared__ float invS[16];          // 1/total rowsum per q

    // XCD swizzle: 64 consecutive blocks (one bh) per XCD
    int swz = (blockIdx.x & 7) * 1024 + (blockIdx.x >> 3);
    int bh = swz >> 6;
    int q0 = (swz & 63) * 16;
    int wid = threadIdx.x >> 6;
    int lane = threadIdx.x & 63;
    int l15 = lane & 15, lg = lane >> 4;

    const short* Qb = Qh + (size_t)bh * NQ * 64;
    const short* Kb = Kh + (size_t)bh * NKP * 64;
    const short* Vb = Vt + (size_t)bh * 64 * NKP;
    const int is32 = *flag;

    // Q fragments (B-operand of swapped QK^T): row = q0 + l15
    bf16x8 aq0 = *(const bf16x8*)(Qb + (size_t)(q0 + l15) * 64 + lg * 8);
    bf16x8 aq1 = *(const bf16x8*)(Qb + (size_t)(q0 + l15) * 64 + 32 + lg * 8);

    size_t qrow = (size_t)bh * NQ + q0 + l15;
    const int kkw = wid * 272;                       // wave's kk window
    const int rofs = ((l15 >> 2) << 3) + (l15 & 3);  // interleaved K-row offset

    // mask preload, 9-deep, in REGISTERS (loop fully unrolled everywhere)
    u32x2 mu9[9];
#pragma unroll
    for (int pp = 0; pp < 9; ++pp) {
        int kkb = kkw + pp * 32 + lg * 8;
        if (is32) {
            unsigned mlo = 0, mhi = 0;
            if (kkb < NK) {
                int4 ma = *(const int4*)(mi + qrow * NK + kkb);
                int4 mc = *(const int4*)(mi + qrow * NK + kkb + 4);
                mlo = (ma.x ? 1u : 0u) | (ma.y ? 0x100u : 0u) |
                      (ma.z ? 0x10000u : 0u) | (ma.w ? 0x1000000u : 0u);
                mhi = (mc.x ? 1u : 0u) | (mc.y ? 0x100u : 0u) |
                      (mc.z ? 0x10000u : 0u) | (mc.w ? 0x1000000u : 0u);
            }
            mu9[pp] = u32x2{mlo, mhi};
        } else {
            mu9[pp] = (kkb < NK) ? *(const u32x2*)(mb + qrow * NK + kkb)
                                 : u32x2{0u, 0u};
        }
    }

    f32x4 po[4];
#pragma unroll
    for (int dt = 0; dt < 4; dt++) po[dt] = f32x4{0.f, 0.f, 0.f, 0.f};
    float rs = 0.f;

#pragma unroll
    for (int pp = 0; pp < 9; ++pp) {
        int ofs = pp * 32 + lg * 8;                // lane's slice offset in window
        int base = kkw + pp * 32;
        int kkb = base + lg * 8;                   // lane's 8 consecutive kk
        // K loads (interleaved rows)
        const short* Kr0 = Kb + (size_t)(base + rofs) * 64;
        bf16x8 k0a = *(const bf16x8*)(Kr0 + lg * 8);
        bf16x8 k0b = *(const bf16x8*)(Kr0 + 32 + lg * 8);
        bf16x8 k1a = *(const bf16x8*)(Kr0 + 256 + lg * 8);       // +4 rows
        bf16x8 k1b = *(const bf16x8*)(Kr0 + 256 + 32 + lg * 8);
        // V loads
        bf16x8 bv0 = *(const bf16x8*)(Vb + (size_t)(l15) * NKP + kkb);
        bf16x8 bv1 = *(const bf16x8*)(Vb + (size_t)(16 + l15) * NKP + kkb);
        bf16x8 bv2 = *(const bf16x8*)(Vb + (size_t)(32 + l15) * NKP + kkb);
        bf16x8 bv3 = *(const bf16x8*)(Vb + (size_t)(48 + l15) * NKP + kkb);
        unsigned mlo = mu9[pp][0], mhi = mu9[pp][1];

        __builtin_amdgcn_s_setprio(1);
        // QK^T
        f32x4 s0 = {0.f, 0.f, 0.f, 0.f}, s1 = {0.f, 0.f, 0.f, 0.f};
        s0 = __builtin_amdgcn_mfma_f32_16x16x32_bf16(k0a, aq0, s0, 0, 0, 0);
        s0 = __builtin_amdgcn_mfma_f32_16x16x32_bf16(k0b, aq1, s0, 0, 0, 0);
        s1 = __builtin_amdgcn_mfma_f32_16x16x32_bf16(k1a, aq0, s1, 0, 0, 0);
        s1 = __builtin_amdgcn_mfma_f32_16x16x32_bf16(k1b, aq1, s1, 0, 0, 0);
        // exp + pack; window guard: ofs >= 272 belongs to the NEXT wave
        bool live = (kkb < NKM) && (ofs < 272);
        bf16x8 pa;
        float e;
#pragma unroll
        for (int r = 0; r < 4; r++) {
            e = (live && (((mlo >> (8 * r)) & 0xffu) == 0u)) ? __expf(s0[r] * 0.125f) : 0.f;
            rs += e;
            pa[r] = f2bf(e);
        }
#pragma unroll
        for (int r = 0; r < 4; r++) {
            e = (live && (((mhi >> (8 * r)) & 0xffu) == 0u)) ? __expf(s1[r] * 0.125f) : 0.f;
            rs += e;
            pa[4 + r] = f2bf(e);
        }
        // PV (unnormalized accumulate) using live registers
        po[0] = __builtin_amdgcn_mfma_f32_16x16x32_bf16(pa, bv0, po[0], 0, 0, 0);
        po[1] = __builtin_amdgcn_mfma_f32_16x16x32_bf16(pa, bv1, po[1], 0, 0, 0);
        po[2] = __builtin_amdgcn_mfma_f32_16x16x32_bf16(pa, bv2, po[2], 0, 0, 0);
        po[3] = __builtin_amdgcn_mfma_f32_16x16x32_bf16(pa, bv3, po[3], 0, 0, 0);
        __builtin_amdgcn_s_setprio(0);

        // stash P (guard keeps index < PSTR and wave-private)
        if (ofs < 272)
            *(bf16x8*)(&Pl[wid][l15][ofs]) = pa;
    }

    // rowsum reduce: lanes with same l15 (q) are 16 apart
    rs += __shfl_xor(rs, 16);
    rs += __shfl_xor(rs, 32);
    if (lg == 0) redS[wid][l15] = rs;
    __syncthreads();
    if (threadIdx.x < 16)
        invS[threadIdx.x] = 1.f / (redS[0][threadIdx.x] + redS[1][threadIdx.x] +
                                   redS[2][threadIdx.x] + redS[3][threadIdx.x]);
    __syncthreads();

    // ---- att: contiguous 128B-aligned NT linear sweep (16x1064 f32 tile) ----
    float* attT = att + (size_t)(bh * NQ + q0) * NKM;
#pragma unroll 4
    for (int j = 0; j < 17; ++j) {
        int f = j * 256 + threadIdx.x;          // float4 index, < 4256
        if (f < 4256) {
            int r = f / 266;                    // 266 float4 per row (1064/4)
            int c = (f - r * 266) * 4;          // float col 0..1060
            int w = c / 272;                    // owning wave window
            int ofs = c - w * 272;
            short4v p = *(const short4v*)(&Pl[w][r][ofs]);
            float iv = invS[r];
            f32x4 o = {bf2f(p[0]) * iv, bf2f(p[1]) * iv,
                       bf2f(p[2]) * iv, bf2f(p[3]) * iv};
            __builtin_nontemporal_store(o, (f32x4*)(attT + (size_t)f * 4));
        }
    }
    __syncthreads();                            // all Pl reads done

    // ---- cross-wave O reduce (reuse own Pl region) ----
    float* OredW = (float*)&Pl[wid][0][0];      // [16][68] f32 = 4352 B
#pragma unroll
    for (int dt = 0; dt < 4; dt++)
#pragma unroll
        for (int r = 0; r < 4; r++)
            OredW[(lg * 4 + r) * 68 + dt * 16 + l15] = po[dt][r];
    __syncthreads();

    int tq = threadIdx.x >> 4;                  // 0..15
    int d0 = (threadIdx.x & 15) * 4;            // 0..60
    float4 o = {0.f, 0.f, 0.f, 0.f};
#pragma unroll
    for (int w = 0; w < 4; w++) {
        const float* Or = (const float*)&Pl[w][0][0];
        float4 v = *(const float4*)(&Or[tq * 68 + d0]);
        o.x += v.x; o.y += v.y; o.z += v.z; o.w += v.w;
    }
    float invt = invS[tq];
    int b = bh >> 4, h = bh & 15;
    short4v sv;
    sv[0] = f2bf(o.x * invt); sv[1] = f2bf(o.y * invt);
    sv[2] = f2bf(o.z * invt); sv[3] = f2bf(o.w * invt);
    *(short4v*)(Ow + ((size_t)b * NQ + q0 + tq) * DM + h * 64 + d0) = sv;
}

extern "C" void kernel_launch(void* const* d_in, const int* in_sizes, int n_in,
                              void* d_out, int out_size, void* d_ws, size_t ws_size,
                              hipStream_t stream) {
    const float* queries = (const float*)d_in[0];
    const float* keys    = (const float*)d_in[1];
    const float* values  = (const float*)d_in[2];
    const void*  mask    = d_in[3];
    const float* Wq = (const float*)d_in[4];
    const float* bq = (const float*)d_in[5];
    const float* Wk = (const float*)d_in[6];
    const float* bk = (const float*)d_in[7];
    const float* Wv = (const float*)d_in[8];
    const float* bv = (const float*)d_in[9];
    const float* Wo = (const float*)d_in[10];
    const float* bo = (const float*)d_in[11];
    const float* m_k = (const float*)d_in[12];
    const float* m_v = (const float*)d_in[13];

    // workspace layout (~130 MB)
    short* WqT = (short*)d_ws;
    short* WkT = WqT + (size_t)DM * DM;
    short* WvT = WkT + (size_t)DM * DM;
    short* WoT = WvT + (size_t)DM * DM;
    short* Qh  = WoT + (size_t)DM * DM;                 // [128][1024][64]
    short* Kh  = Qh + (size_t)B_ * H_ * NQ * DK;        // [128][1104][64]
    short* Vt  = Kh + (size_t)B_ * H_ * NKP * DK;       // [128][64][1104]
    short* Ow  = Vt + (size_t)B_ * H_ * DK * NKP;       // [8192][1024]
    char*  after = (char*)(Ow + (size_t)B_ * NQ * DM);
    int*   flag = (int*)after;
    short* Qbf  = (short*)(after + 64);                 // bf16 q/k/v inputs
    short* Kbf  = Qbf + (size_t)B_ * NQ * DM;
    short* Vbf  = Kbf + (size_t)B_ * NQ * DM;

    float* outO = (float*)d_out;                         // 8*1024*1024
    float* att  = outO + (size_t)B_ * NQ * DM;           // 8*16*1024*1064

    detect_mask_kernel<<<1, 256, 0, stream>>>((const unsigned int*)mask, 4096, flag);

    dim3 tg(32, 32, 4);
    transpose_w_kernel<<<tg, 256, 0, stream>>>(Wq, WqT, Wk, WkT, Wv, WvT, Wo, WoT);

    convert_bf16_kernel<<<4096, 256, 0, stream>>>(queries, keys, values, Qbf);

    gemm_tile_kernel<0><<<512, 256, 0, stream>>>(Qbf, WqT, bq, nullptr, Qh);
    gemm_tile_kernel<1><<<512, 256, 0, stream>>>(Kbf, WkT, bk, nullptr, Kh);
    gemm_tile_kernel<2><<<512, 256, 0, stream>>>(Vbf, WvT, bv, nullptr, Vt);

    fill_mem_kernel<<<2560, 256, 0, stream>>>(m_k, m_v, Kh, Vt);

    attn_fused_kernel<<<8192, 256, 0, stream>>>(Qh, Kh, Vt,
                                                (const unsigned char*)mask, (const int*)mask,
                                                flag, att, Ow);

    gemm_tile_kernel<3><<<512, 256, 0, stream>>>(Ow, WoT, bo, outO, nullptr);
}